// Round 10
// baseline (110.966 us; speedup 1.0000x reference)
//
#include <hip/hip_runtime.h>

// MultiboxLoss anchor matching: B=64, T=100, A=8732, NUM_CLASSES=21
// out = [loc (B,A,4) f32][conf (B,A) as f32]
// Round 14: lgkm decoupling. R10/R12/R13 busy-time invariant ~36us,
// wall/busy 1.32-1.39 -> in-wave stall, not tail. Cause: hot loop mixes
// SMEM s_loads (out-of-order -> lgkmcnt(0) drain), sh_area ds_read, and
// lane0 ds_writes on ONE counter: every iter exposes raw SMEM latency.
// Fix: (1) drop sh_area entirely — compute per-t areas in VALU from SGPR
// box coords (bit-identical _rn ops; no LDS read, no staging barrier);
// (2) software-pipeline box s_loads one iteration ahead (c/n swap, clamped
// prefetch addr) so the drain hits loads issued a full iter earlier.
// Else identical to R13 (exact-fit 20x64 grid, u16 pa, 4-op div).
//   ws: [0, 51200): u64 keys[B*T]        — (iou_bits<<32)|~anchor, atomicMax
//       [51200, +B*A*2): u16 pa[B*A]     — per-anchor (gi | pos<<7)
#define BB 64
#define TT 100
#define AA 8732
#define CHUNK 512                         // anchors per block (256 thr x 2)
#define NCHUNK 20                         // padded: 20*512 = 10240 >= 8732

typedef unsigned long long u64;
typedef unsigned int u32;
typedef unsigned short u16;

// Faithful (<=1ulp) f32 division, 4 VALU, no VCC. Inputs always normal
// (u >= 4e-4); i == 0 returns exactly 0. q = i*r(1+e); rem = -i*e (exact
// fma); q' = q + rem*r = (i/u)(1-e^2), e ~ 2^-23 => e^2 negligible.
__device__ __forceinline__ float fdiv_faithful(float i, float u) {
    float r = __builtin_amdgcn_rcpf(u);                     // v_rcp_f32
    float q = __fmul_rn(i, r);
    float rem = __builtin_fmaf(-u, q, i);                   // exact remainder
    return __builtin_fmaf(rem, r, q);
}

// Bit-matching (vs numpy f32) intersection/union: _rn blocks fp-contract.
// dx,dy <= 0.3 < 1 always (input bounds), so min(.,1) is a numeric no-op —
// lets LLVM collapse max+min into the VOP3 clamp/med3 form.
__device__ __forceinline__ float iou_f(float bx1, float by1, float bx2, float by2, float areab,
                                       float ax1, float ay1, float ax2, float ay2, float areaa) {
    float dx = fminf(fmaxf(__fsub_rn(fminf(bx2, ax2), fmaxf(bx1, ax1)), 0.0f), 1.0f);
    float dy = fminf(fmaxf(__fsub_rn(fminf(by2, ay2), fmaxf(by1, ay1)), 0.0f), 1.0f);
    float inter = __fmul_rn(dx, dy);
    float uni = __fsub_rn(__fadd_rn(areab, areaa), inter);
    return fdiv_faithful(inter, uni);
}

// 4 interleaved wave64 max reductions, DPP fused into v_max_f32 (1 inst
// per stage per chain). Lane 63 of each holds the wave max. 4-chain
// interleave gives 3-inst spacing => DPP read-after-write hazard met.
// s_nop 1 guards entry, s_nop 0 guards exit (compiler can't see hazards
// inside the asm). bound_ctrl off: invalid lanes keep dest = max-identity.
__device__ __forceinline__ void wave_max63_x4(float& x0, float& x1, float& x2, float& x3) {
    asm volatile(
        "s_nop 1\n\t"
        "v_max_f32 %0, %0, %0 row_shr:1\n\t"
        "v_max_f32 %1, %1, %1 row_shr:1\n\t"
        "v_max_f32 %2, %2, %2 row_shr:1\n\t"
        "v_max_f32 %3, %3, %3 row_shr:1\n\t"
        "v_max_f32 %0, %0, %0 row_shr:2\n\t"
        "v_max_f32 %1, %1, %1 row_shr:2\n\t"
        "v_max_f32 %2, %2, %2 row_shr:2\n\t"
        "v_max_f32 %3, %3, %3 row_shr:2\n\t"
        "v_max_f32 %0, %0, %0 row_shr:4\n\t"
        "v_max_f32 %1, %1, %1 row_shr:4\n\t"
        "v_max_f32 %2, %2, %2 row_shr:4\n\t"
        "v_max_f32 %3, %3, %3 row_shr:4\n\t"
        "v_max_f32 %0, %0, %0 row_shr:8\n\t"
        "v_max_f32 %1, %1, %1 row_shr:8\n\t"
        "v_max_f32 %2, %2, %2 row_shr:8\n\t"
        "v_max_f32 %3, %3, %3 row_shr:8\n\t"
        "v_max_f32 %0, %0, %0 row_bcast:15\n\t"
        "v_max_f32 %1, %1, %1 row_bcast:15\n\t"
        "v_max_f32 %2, %2, %2 row_bcast:15\n\t"
        "v_max_f32 %3, %3, %3 row_bcast:15\n\t"
        "v_max_f32 %0, %0, %0 row_bcast:31\n\t"
        "v_max_f32 %1, %1, %1 row_bcast:31\n\t"
        "v_max_f32 %2, %2, %2 row_bcast:31\n\t"
        "v_max_f32 %3, %3, %3 row_bcast:31\n\t"
        "s_nop 0"
        : "+v"(x0), "+v"(x1), "+v"(x2), "+v"(x3));
}

__global__ __launch_bounds__(256) void k_init(u64* __restrict__ keys) {
    int i = blockIdx.x * 256 + threadIdx.x;
    if (i < BB * TT) keys[i] = 0ULL;
}

// Fused pass: block = (chunk, b). 256 threads = 4 waves, each wave owns
// 128 anchors (2/thread) over the FULL t range (25 iters). Boxes via SMEM
// with one-iteration software prefetch; areas computed in VALU; no LDS
// reads in the hot loop. Grid 20x64 = 1280.
__global__ __launch_bounds__(256) void k_phaseA(const float* __restrict__ targets,
                                                const float* __restrict__ anchors,
                                                u64* __restrict__ keys,
                                                u16* __restrict__ pa) {
    const int b = blockIdx.y;
    const int tid = threadIdx.x;
    const int a0 = blockIdx.x * CHUNK + tid * 2;  // AA even => pair never straddles
    const bool valid = a0 < AA;
    const int lane = tid & 63, wv = tid >> 6;     // wv 0..3

    __shared__ u64 sh_red[4][TT];                 // [wave][t] per-target winners

    // Anchor point-form. OOB lanes use dummy (0,0,0,0,area=1): intersection
    // is exactly 0 => IoU = 0/(areab+1) = 0 exactly; dummy entries can only
    // win a per-t reduction at value 0 and lose the keys atomicMax to any
    // real anchor (smaller index => larger ~g).
    float ax10 = 0.f, ay10 = 0.f, ax20 = 0.f, ay20 = 0.f, aa0 = 1.f;
    float ax11 = 0.f, ay11 = 0.f, ax21 = 0.f, ay21 = 0.f, aa1 = 1.f;
    if (valid) {
        const float4* anc = (const float4*)(anchors + (size_t)a0 * 4);
        float4 c0 = anc[0], c1 = anc[1];
        float hx0 = __fmul_rn(c0.z, 0.5f), hy0 = __fmul_rn(c0.w, 0.5f);
        ax10 = __fsub_rn(c0.x, hx0); ay10 = __fsub_rn(c0.y, hy0);
        ax20 = __fadd_rn(c0.x, hx0); ay20 = __fadd_rn(c0.y, hy0);
        aa0 = __fmul_rn(__fsub_rn(ax20, ax10), __fsub_rn(ay20, ay10));
        float hx1 = __fmul_rn(c1.z, 0.5f), hy1 = __fmul_rn(c1.w, 0.5f);
        ax11 = __fsub_rn(c1.x, hx1); ay11 = __fsub_rn(c1.y, hy1);
        ax21 = __fadd_rn(c1.x, hx1); ay21 = __fadd_rn(c1.y, hy1);
        aa1 = __fmul_rn(__fsub_rn(ax21, ax11), __fsub_rn(ay21, ay11));
    }

    float best0 = -1.f, best1 = -1.f;     // iou >= 0 > -1: always replaced on first t
    int gi0 = 0, gi1 = 0;
    const u32 wave_base = (u32)blockIdx.x * CHUNK + (u32)wv * 128u;

    const float* tbase = targets + (size_t)b * TT * 5;

    // current 4-box window (wave-uniform -> SGPRs)
    float c[20];
    #pragma unroll
    for (int j = 0; j < 20; ++j) c[j] = tbase[j];

    for (int t = 0; t < TT; t += 4) {
        // prefetch next window (clamped addr: in-bounds, unused on last iter)
        const int tn = (t + 4 < TT) ? (t + 4) : (TT - 4);
        const float* nb = tbase + (size_t)tn * 5;
        float n[20];
        #pragma unroll
        for (int j = 0; j < 20; ++j) n[j] = nb[j];

        const float B0x = c[0],  B0y = c[1],  B0z = c[2],  B0w = c[3];
        const float B1x = c[5],  B1y = c[6],  B1z = c[7],  B1w = c[8];
        const float B2x = c[10], B2y = c[11], B2z = c[12], B2w = c[13];
        const float B3x = c[15], B3y = c[16], B3z = c[17], B3w = c[18];
        // per-t areas in VALU (bit-identical _rn ops; no LDS read)
        const float ar0 = __fmul_rn(__fsub_rn(B0z, B0x), __fsub_rn(B0w, B0y));
        const float ar1 = __fmul_rn(__fsub_rn(B1z, B1x), __fsub_rn(B1w, B1y));
        const float ar2 = __fmul_rn(__fsub_rn(B2z, B2x), __fsub_rn(B2w, B2y));
        const float ar3 = __fmul_rn(__fsub_rn(B3z, B3x), __fsub_rn(B3w, B3y));

        // 8 independent IoUs: 4-op Markstein divs pipeline freely (no VCC)
        float v00 = iou_f(B0x, B0y, B0z, B0w, ar0, ax10, ay10, ax20, ay20, aa0);
        float v01 = iou_f(B0x, B0y, B0z, B0w, ar0, ax11, ay11, ax21, ay21, aa1);
        float v10 = iou_f(B1x, B1y, B1z, B1w, ar1, ax10, ay10, ax20, ay20, aa0);
        float v11 = iou_f(B1x, B1y, B1z, B1w, ar1, ax11, ay11, ax21, ay21, aa1);
        float v20 = iou_f(B2x, B2y, B2z, B2w, ar2, ax10, ay10, ax20, ay20, aa0);
        float v21 = iou_f(B2x, B2y, B2z, B2w, ar2, ax11, ay11, ax21, ay21, aa1);
        float v30 = iou_f(B3x, B3y, B3z, B3w, ar3, ax10, ay10, ax20, ay20, aa0);
        float v31 = iou_f(B3x, B3y, B3z, B3w, ar3, ax11, ay11, ax21, ay21, aa1);

        // per-anchor argmax over t: ascending t, strict > => first-t-wins
        if (v00 > best0) { best0 = v00; gi0 = t; }
        if (v10 > best0) { best0 = v10; gi0 = t + 1; }
        if (v20 > best0) { best0 = v20; gi0 = t + 2; }
        if (v30 > best0) { best0 = v30; gi0 = t + 3; }
        if (v01 > best1) { best1 = v01; gi1 = t; }
        if (v11 > best1) { best1 = v11; gi1 = t + 1; }
        if (v21 > best1) { best1 = v21; gi1 = t + 2; }
        if (v31 > best1) { best1 = v31; gi1 = t + 3; }

        // per-t argmax over this wave's 128 anchors
        float vm0 = fmaxf(v00, v01), vm1 = fmaxf(v10, v11);
        float vm2 = fmaxf(v20, v21), vm3 = fmaxf(v30, v31);
        float w0 = vm0, w1 = vm1, w2 = vm2, w3 = vm3;
        wave_max63_x4(w0, w1, w2, w3);
        u32 wm0 = (u32)__builtin_amdgcn_readlane(__float_as_int(w0), 63);
        u32 wm1 = (u32)__builtin_amdgcn_readlane(__float_as_int(w1), 63);
        u32 wm2 = (u32)__builtin_amdgcn_readlane(__float_as_int(w2), 63);
        u32 wm3 = (u32)__builtin_amdgcn_readlane(__float_as_int(w3), 63);
        // winner lane = smallest lane matching max (first-anchor-wins);
        // pair-bit from the v1>v0 ballot (strict >: first-index-wins in pair)
        u64 me0 = __ballot(vm0 == __uint_as_float(wm0));
        u64 mp0 = __ballot(v01 > v00);
        u64 me1 = __ballot(vm1 == __uint_as_float(wm1));
        u64 mp1 = __ballot(v11 > v10);
        u64 me2 = __ballot(vm2 == __uint_as_float(wm2));
        u64 mp2 = __ballot(v21 > v20);
        u64 me3 = __ballot(vm3 == __uint_as_float(wm3));
        u64 mp3 = __ballot(v31 > v30);
        u32 wl0 = (u32)(__ffsll((long long)me0) - 1);
        u32 wl1 = (u32)(__ffsll((long long)me1) - 1);
        u32 wl2 = (u32)(__ffsll((long long)me2) - 1);
        u32 wl3 = (u32)(__ffsll((long long)me3) - 1);
        u32 g0 = wave_base + wl0 * 2u + (u32)((mp0 >> wl0) & 1ULL);
        u32 g1 = wave_base + wl1 * 2u + (u32)((mp1 >> wl1) & 1ULL);
        u32 g2 = wave_base + wl2 * 2u + (u32)((mp2 >> wl2) & 1ULL);
        u32 g3 = wave_base + wl3 * 2u + (u32)((mp3 >> wl3) & 1ULL);
        if (lane == 0) {
            // [wv][t..t+3] contiguous => compiler can merge to b128 stores
            u64* r = &sh_red[wv][t];
            r[0] = (((u64)wm0) << 32) | (u32)~g0;
            r[1] = (((u64)wm1) << 32) | (u32)~g1;
            r[2] = (((u64)wm2) << 32) | (u32)~g2;
            r[3] = (((u64)wm3) << 32) | (u32)~g3;
        }

        #pragma unroll
        for (int j = 0; j < 20; ++j) c[j] = n[j];
    }
    __syncthreads();   // sh_red complete

    // per-(b,t) winner across this block's 512 anchors
    if (tid < TT) {
        u64 m0 = sh_red[0][tid], m1 = sh_red[1][tid];
        u64 m2 = sh_red[2][tid], m3 = sh_red[3][tid];
        u64 m = m0 > m1 ? m0 : m1;
        if (m2 > m) m = m2;
        if (m3 > m) m = m3;
        atomicMax(&keys[b * TT + tid], m);
    }

    // per-anchor result: complete in-block (full t range covered here)
    if (valid) {
        u32 f0 = (u32)gi0 | (best0 >= 0.5f ? 0x80u : 0u);
        u32 f1 = (u32)gi1 | (best1 >= 0.5f ? 0x80u : 0u);
        *(u32*)(pa + (size_t)b * AA + a0) = f0 | (f1 << 16);  // 4B-aligned
    }
}

// Encode: thread per (b,a). Override via LDS atomicMax scatter
// (value 0x100|t monotone in t => last-wins, matching .at[].set semantics).
__global__ __launch_bounds__(256) void k_encode(const float* __restrict__ targets,
                                                const float* __restrict__ anchors,
                                                const u64* __restrict__ keys,
                                                const u16* __restrict__ pa,
                                                float* __restrict__ out) {
    const int b = blockIdx.y;
    const int a = blockIdx.x * 256 + threadIdx.x;

    __shared__ float sh_t[TT][6];   // x1,y1,x2,y2,label
    __shared__ u32 sh_ov[256];

    sh_ov[threadIdx.x] = 0;
    __syncthreads();
    for (int t = threadIdx.x; t < TT; t += 256) {
        const float* tg = targets + ((size_t)b * TT + t) * 5;
        sh_t[t][0] = tg[0]; sh_t[t][1] = tg[1];
        sh_t[t][2] = tg[2]; sh_t[t][3] = tg[3];
        sh_t[t][4] = tg[4];
        u32 at = ~(u32)(keys[b * TT + t] & 0xFFFFFFFFu);
        if ((at >> 8) == (u32)blockIdx.x)
            atomicMax(&sh_ov[at & 255], 0x100u | (u32)t);
    }
    __syncthreads();
    if (a >= AA) return;

    u32 ov = sh_ov[threadIdx.x];
    u32 v = pa[(size_t)b * AA + a];
    int gi; bool pos;
    if (ov) { gi = (int)(ov & 0x7F); pos = true; }
    else     { gi = (int)(v & 0x7F); pos = (v & 0x80) != 0; }

    const float4 anc = *(const float4*)(anchors + (size_t)a * 4);
    const float mx1 = sh_t[gi][0], my1 = sh_t[gi][1], mx2 = sh_t[gi][2], my2 = sh_t[gi][3];
    const float cx = (mx1 + mx2) * 0.5f, cy = (my1 + my2) * 0.5f;
    const float w = mx2 - mx1, h = my2 - my1;
    const float l0 = (cx - anc.x) / (0.1f * anc.z);
    const float l1 = (cy - anc.y) / (0.1f * anc.w);
    const float l2 = logf(w / anc.z) / 0.2f;
    const float l3 = logf(h / anc.w) / 0.2f;

    const size_t base = ((size_t)b * AA + a) * 4;
    *(float4*)(out + base) = make_float4(l0, l1, l2, l3);
    float conf = pos ? (float)(int)(sh_t[gi][4] + 1.0f) : 0.0f;
    out[(size_t)BB * AA * 4 + (size_t)b * AA + a] = conf;
}

extern "C" void kernel_launch(void* const* d_in, const int* in_sizes, int n_in,
                              void* d_out, int out_size, void* d_ws, size_t ws_size,
                              hipStream_t stream) {
    const float* targets = (const float*)d_in[0];  // (B,T,5)
    const float* anchors = (const float*)d_in[1];  // (A,4)
    float* out = (float*)d_out;
    u64* keys = (u64*)d_ws;                                // 51.2 KB
    u16* pa = (u16*)((char*)d_ws + (size_t)BB * TT * 8);   // 1.09 MB

    k_init<<<(BB * TT + 255) / 256, 256, 0, stream>>>(keys);
    dim3 gA(NCHUNK, BB);
    k_phaseA<<<gA, 256, 0, stream>>>(targets, anchors, keys, pa);
    dim3 gE((AA + 255) / 256, BB);
    k_encode<<<gE, 256, 0, stream>>>(targets, anchors, keys, pa, out);
}

// Round 11
// 106.531 us; speedup vs baseline: 1.0416x; 1.0416x over previous
//
#include <hip/hip_runtime.h>

// MultiboxLoss anchor matching: B=64, T=100, A=8732, NUM_CLASSES=21
// out = [loc (B,A,4) f32][conf (B,A) as f32]
// Round 15: smaller work quantum. R14 prefetch FAILED (53.1us: FETCH
// doubled 663->1162MB, SGPR 48->64, 20-reg copy/iter) — reverted to R13
// loop body (direct SMEM box loads + LDS areas). Work accounting across
// R12/R13: wave-iters 115.2k/128k, busy ~36us invariant; R13's 14.7%
// padding was pure loss. This round: 192-thr blocks (3 waves x 128
// anchors), NCHUNK=23 -> 8832 anchors = 1.1% pad. Wave-iters 110.4k
// (-13.8% vs R13). All 1472 blocks co-resident (3.3KB LDS, 24 VGPR);
// 3-wave quantum packs CUs evenly. Keeps in-block-complete per-anchor
// argmax -> u16 pa, cheap encode.
//   ws: [0, 51200): u64 keys[B*T]        — (iou_bits<<32)|~anchor, atomicMax
//       [51200, +B*A*2): u16 pa[B*A]     — per-anchor (gi | pos<<7)
#define BB 64
#define TT 100
#define AA 8732
#define CHUNK 384                         // anchors per block (192 thr x 2)
#define NCHUNK 23                         // 23*384 = 8832 >= 8732 (1.1% pad)
#define NTHR 192                          // 3 waves

typedef unsigned long long u64;
typedef unsigned int u32;
typedef unsigned short u16;

// Faithful (<=1ulp) f32 division, 4 VALU, no VCC. Inputs always normal
// (u >= 4e-4); i == 0 returns exactly 0. q = i*r(1+e); rem = -i*e (exact
// fma); q' = q + rem*r = (i/u)(1-e^2), e ~ 2^-23 => e^2 negligible.
__device__ __forceinline__ float fdiv_faithful(float i, float u) {
    float r = __builtin_amdgcn_rcpf(u);                     // v_rcp_f32
    float q = __fmul_rn(i, r);
    float rem = __builtin_fmaf(-u, q, i);                   // exact remainder
    return __builtin_fmaf(rem, r, q);
}

// Bit-matching (vs numpy f32) intersection/union: _rn blocks fp-contract.
// dx,dy <= 0.3 < 1 always (input bounds), so min(.,1) is a numeric no-op —
// lets LLVM collapse max+min into the VOP3 clamp/med3 form.
__device__ __forceinline__ float iou_f(float bx1, float by1, float bx2, float by2, float areab,
                                       float ax1, float ay1, float ax2, float ay2, float areaa) {
    float dx = fminf(fmaxf(__fsub_rn(fminf(bx2, ax2), fmaxf(bx1, ax1)), 0.0f), 1.0f);
    float dy = fminf(fmaxf(__fsub_rn(fminf(by2, ay2), fmaxf(by1, ay1)), 0.0f), 1.0f);
    float inter = __fmul_rn(dx, dy);
    float uni = __fsub_rn(__fadd_rn(areab, areaa), inter);
    return fdiv_faithful(inter, uni);
}

// 4 interleaved wave64 max reductions, DPP fused into v_max_f32 (1 inst
// per stage per chain). Lane 63 of each holds the wave max. 4-chain
// interleave gives 3-inst spacing => DPP read-after-write hazard met.
// s_nop 1 guards entry, s_nop 0 guards exit (compiler can't see hazards
// inside the asm). bound_ctrl off: invalid lanes keep dest = max-identity.
__device__ __forceinline__ void wave_max63_x4(float& x0, float& x1, float& x2, float& x3) {
    asm volatile(
        "s_nop 1\n\t"
        "v_max_f32 %0, %0, %0 row_shr:1\n\t"
        "v_max_f32 %1, %1, %1 row_shr:1\n\t"
        "v_max_f32 %2, %2, %2 row_shr:1\n\t"
        "v_max_f32 %3, %3, %3 row_shr:1\n\t"
        "v_max_f32 %0, %0, %0 row_shr:2\n\t"
        "v_max_f32 %1, %1, %1 row_shr:2\n\t"
        "v_max_f32 %2, %2, %2 row_shr:2\n\t"
        "v_max_f32 %3, %3, %3 row_shr:2\n\t"
        "v_max_f32 %0, %0, %0 row_shr:4\n\t"
        "v_max_f32 %1, %1, %1 row_shr:4\n\t"
        "v_max_f32 %2, %2, %2 row_shr:4\n\t"
        "v_max_f32 %3, %3, %3 row_shr:4\n\t"
        "v_max_f32 %0, %0, %0 row_shr:8\n\t"
        "v_max_f32 %1, %1, %1 row_shr:8\n\t"
        "v_max_f32 %2, %2, %2 row_shr:8\n\t"
        "v_max_f32 %3, %3, %3 row_shr:8\n\t"
        "v_max_f32 %0, %0, %0 row_bcast:15\n\t"
        "v_max_f32 %1, %1, %1 row_bcast:15\n\t"
        "v_max_f32 %2, %2, %2 row_bcast:15\n\t"
        "v_max_f32 %3, %3, %3 row_bcast:15\n\t"
        "v_max_f32 %0, %0, %0 row_bcast:31\n\t"
        "v_max_f32 %1, %1, %1 row_bcast:31\n\t"
        "v_max_f32 %2, %2, %2 row_bcast:31\n\t"
        "v_max_f32 %3, %3, %3 row_bcast:31\n\t"
        "s_nop 0"
        : "+v"(x0), "+v"(x1), "+v"(x2), "+v"(x3));
}

__global__ __launch_bounds__(256) void k_init(u64* __restrict__ keys) {
    int i = blockIdx.x * 256 + threadIdx.x;
    if (i < BB * TT) keys[i] = 0ULL;
}

// Fused pass: block = (chunk, b). 192 threads = 3 waves, each wave owns
// 128 anchors (2/thread) over the FULL t range (25 iters). Boxes via SMEM
// (uniform addr), areas via LDS. Grid 23x64 = 1472, all co-resident.
__global__ __launch_bounds__(NTHR) void k_phaseA(const float* __restrict__ targets,
                                                 const float* __restrict__ anchors,
                                                 u64* __restrict__ keys,
                                                 u16* __restrict__ pa) {
    const int b = blockIdx.y;
    const int tid = threadIdx.x;
    const int a0 = blockIdx.x * CHUNK + tid * 2;  // AA even => pair never straddles
    const bool valid = a0 < AA;
    const int lane = tid & 63, wv = tid >> 6;     // wv 0..2

    __shared__ __align__(16) float sh_area[TT];   // precomputed box area
    __shared__ u64 sh_red[3][TT];                 // [wave][t] per-target winners

    if (tid < TT) {
        const float* tg = targets + ((size_t)b * TT + tid) * 5;
        sh_area[tid] = __fmul_rn(__fsub_rn(tg[2], tg[0]), __fsub_rn(tg[3], tg[1]));
    }
    __syncthreads();

    // Anchor point-form. OOB lanes use dummy (0,0,0,0,area=1): intersection
    // is exactly 0 => IoU = 0/(areab+1) = 0 exactly. Dummy entries can only
    // win a per-t reduction at value 0 and lose the keys atomicMax to any
    // real anchor (dummy index > real => ~g smaller => loses ties).
    float ax10 = 0.f, ay10 = 0.f, ax20 = 0.f, ay20 = 0.f, aa0 = 1.f;
    float ax11 = 0.f, ay11 = 0.f, ax21 = 0.f, ay21 = 0.f, aa1 = 1.f;
    if (valid) {
        const float4* anc = (const float4*)(anchors + (size_t)a0 * 4);
        float4 c0 = anc[0], c1 = anc[1];
        float hx0 = __fmul_rn(c0.z, 0.5f), hy0 = __fmul_rn(c0.w, 0.5f);
        ax10 = __fsub_rn(c0.x, hx0); ay10 = __fsub_rn(c0.y, hy0);
        ax20 = __fadd_rn(c0.x, hx0); ay20 = __fadd_rn(c0.y, hy0);
        aa0 = __fmul_rn(__fsub_rn(ax20, ax10), __fsub_rn(ay20, ay10));
        float hx1 = __fmul_rn(c1.z, 0.5f), hy1 = __fmul_rn(c1.w, 0.5f);
        ax11 = __fsub_rn(c1.x, hx1); ay11 = __fsub_rn(c1.y, hy1);
        ax21 = __fadd_rn(c1.x, hx1); ay21 = __fadd_rn(c1.y, hy1);
        aa1 = __fmul_rn(__fsub_rn(ax21, ax11), __fsub_rn(ay21, ay11));
    }

    float best0 = -1.f, best1 = -1.f;     // iou >= 0 > -1: always replaced on first t
    int gi0 = 0, gi1 = 0;
    const u32 wave_base = (u32)blockIdx.x * CHUNK + (u32)wv * 128u;

    const float* tbase = targets + (size_t)b * TT * 5;
    for (int t = 0; t < TT; t += 4) {
        // 4 boxes: wave-uniform addresses -> SMEM s_load, operands fold as
        // SGPR srcs into the IoU VALU ops (no LDS, no VGPR staging).
        const float* tb = tbase + (size_t)t * 5;
        const float B0x = tb[0],  B0y = tb[1],  B0z = tb[2],  B0w = tb[3];
        const float B1x = tb[5],  B1y = tb[6],  B1z = tb[7],  B1w = tb[8];
        const float B2x = tb[10], B2y = tb[11], B2z = tb[12], B2w = tb[13];
        const float B3x = tb[15], B3y = tb[16], B3z = tb[17], B3w = tb[18];
        const float4 arv = *(const float4*)&sh_area[t];   // t%4==0 => 16B aligned
        float ar0 = arv.x, ar1 = arv.y, ar2 = arv.z, ar3 = arv.w;

        // 8 independent IoUs: 4-op Markstein divs pipeline freely (no VCC)
        float v00 = iou_f(B0x, B0y, B0z, B0w, ar0, ax10, ay10, ax20, ay20, aa0);
        float v01 = iou_f(B0x, B0y, B0z, B0w, ar0, ax11, ay11, ax21, ay21, aa1);
        float v10 = iou_f(B1x, B1y, B1z, B1w, ar1, ax10, ay10, ax20, ay20, aa0);
        float v11 = iou_f(B1x, B1y, B1z, B1w, ar1, ax11, ay11, ax21, ay21, aa1);
        float v20 = iou_f(B2x, B2y, B2z, B2w, ar2, ax10, ay10, ax20, ay20, aa0);
        float v21 = iou_f(B2x, B2y, B2z, B2w, ar2, ax11, ay11, ax21, ay21, aa1);
        float v30 = iou_f(B3x, B3y, B3z, B3w, ar3, ax10, ay10, ax20, ay20, aa0);
        float v31 = iou_f(B3x, B3y, B3z, B3w, ar3, ax11, ay11, ax21, ay21, aa1);

        // per-anchor argmax over t: ascending t, strict > => first-t-wins
        if (v00 > best0) { best0 = v00; gi0 = t; }
        if (v10 > best0) { best0 = v10; gi0 = t + 1; }
        if (v20 > best0) { best0 = v20; gi0 = t + 2; }
        if (v30 > best0) { best0 = v30; gi0 = t + 3; }
        if (v01 > best1) { best1 = v01; gi1 = t; }
        if (v11 > best1) { best1 = v11; gi1 = t + 1; }
        if (v21 > best1) { best1 = v21; gi1 = t + 2; }
        if (v31 > best1) { best1 = v31; gi1 = t + 3; }

        // per-t argmax over this wave's 128 anchors
        float vm0 = fmaxf(v00, v01), vm1 = fmaxf(v10, v11);
        float vm2 = fmaxf(v20, v21), vm3 = fmaxf(v30, v31);
        float w0 = vm0, w1 = vm1, w2 = vm2, w3 = vm3;
        wave_max63_x4(w0, w1, w2, w3);
        u32 wm0 = (u32)__builtin_amdgcn_readlane(__float_as_int(w0), 63);
        u32 wm1 = (u32)__builtin_amdgcn_readlane(__float_as_int(w1), 63);
        u32 wm2 = (u32)__builtin_amdgcn_readlane(__float_as_int(w2), 63);
        u32 wm3 = (u32)__builtin_amdgcn_readlane(__float_as_int(w3), 63);
        // winner lane = smallest lane matching max (first-anchor-wins);
        // pair-bit from the v1>v0 ballot (strict >: first-index-wins in pair)
        u64 me0 = __ballot(vm0 == __uint_as_float(wm0));
        u64 mp0 = __ballot(v01 > v00);
        u64 me1 = __ballot(vm1 == __uint_as_float(wm1));
        u64 mp1 = __ballot(v11 > v10);
        u64 me2 = __ballot(vm2 == __uint_as_float(wm2));
        u64 mp2 = __ballot(v21 > v20);
        u64 me3 = __ballot(vm3 == __uint_as_float(wm3));
        u64 mp3 = __ballot(v31 > v30);
        u32 wl0 = (u32)(__ffsll((long long)me0) - 1);
        u32 wl1 = (u32)(__ffsll((long long)me1) - 1);
        u32 wl2 = (u32)(__ffsll((long long)me2) - 1);
        u32 wl3 = (u32)(__ffsll((long long)me3) - 1);
        u32 g0 = wave_base + wl0 * 2u + (u32)((mp0 >> wl0) & 1ULL);
        u32 g1 = wave_base + wl1 * 2u + (u32)((mp1 >> wl1) & 1ULL);
        u32 g2 = wave_base + wl2 * 2u + (u32)((mp2 >> wl2) & 1ULL);
        u32 g3 = wave_base + wl3 * 2u + (u32)((mp3 >> wl3) & 1ULL);
        if (lane == 0) {
            // [wv][t..t+3] contiguous => compiler can merge to b128 stores
            u64* r = &sh_red[wv][t];
            r[0] = (((u64)wm0) << 32) | (u32)~g0;
            r[1] = (((u64)wm1) << 32) | (u32)~g1;
            r[2] = (((u64)wm2) << 32) | (u32)~g2;
            r[3] = (((u64)wm3) << 32) | (u32)~g3;
        }
    }
    __syncthreads();   // sh_red complete

    // per-(b,t) winner across this block's 384 anchors
    if (tid < TT) {
        u64 m0 = sh_red[0][tid], m1 = sh_red[1][tid];
        u64 m2 = sh_red[2][tid];
        u64 m = m0 > m1 ? m0 : m1;
        if (m2 > m) m = m2;
        atomicMax(&keys[b * TT + tid], m);
    }

    // per-anchor result: complete in-block (full t range covered here)
    if (valid) {
        u32 f0 = (u32)gi0 | (best0 >= 0.5f ? 0x80u : 0u);
        u32 f1 = (u32)gi1 | (best1 >= 0.5f ? 0x80u : 0u);
        *(u32*)(pa + (size_t)b * AA + a0) = f0 | (f1 << 16);  // 4B-aligned
    }
}

// Encode: thread per (b,a). Override via LDS atomicMax scatter
// (value 0x100|t monotone in t => last-wins, matching .at[].set semantics).
__global__ __launch_bounds__(256) void k_encode(const float* __restrict__ targets,
                                                const float* __restrict__ anchors,
                                                const u64* __restrict__ keys,
                                                const u16* __restrict__ pa,
                                                float* __restrict__ out) {
    const int b = blockIdx.y;
    const int a = blockIdx.x * 256 + threadIdx.x;

    __shared__ float sh_t[TT][6];   // x1,y1,x2,y2,label
    __shared__ u32 sh_ov[256];

    sh_ov[threadIdx.x] = 0;
    __syncthreads();
    for (int t = threadIdx.x; t < TT; t += 256) {
        const float* tg = targets + ((size_t)b * TT + t) * 5;
        sh_t[t][0] = tg[0]; sh_t[t][1] = tg[1];
        sh_t[t][2] = tg[2]; sh_t[t][3] = tg[3];
        sh_t[t][4] = tg[4];
        u32 at = ~(u32)(keys[b * TT + t] & 0xFFFFFFFFu);
        if ((at >> 8) == (u32)blockIdx.x)
            atomicMax(&sh_ov[at & 255], 0x100u | (u32)t);
    }
    __syncthreads();
    if (a >= AA) return;

    u32 ov = sh_ov[threadIdx.x];
    u32 v = pa[(size_t)b * AA + a];
    int gi; bool pos;
    if (ov) { gi = (int)(ov & 0x7F); pos = true; }
    else     { gi = (int)(v & 0x7F); pos = (v & 0x80) != 0; }

    const float4 anc = *(const float4*)(anchors + (size_t)a * 4);
    const float mx1 = sh_t[gi][0], my1 = sh_t[gi][1], mx2 = sh_t[gi][2], my2 = sh_t[gi][3];
    const float cx = (mx1 + mx2) * 0.5f, cy = (my1 + my2) * 0.5f;
    const float w = mx2 - mx1, h = my2 - my1;
    const float l0 = (cx - anc.x) / (0.1f * anc.z);
    const float l1 = (cy - anc.y) / (0.1f * anc.w);
    const float l2 = logf(w / anc.z) / 0.2f;
    const float l3 = logf(h / anc.w) / 0.2f;

    const size_t base = ((size_t)b * AA + a) * 4;
    *(float4*)(out + base) = make_float4(l0, l1, l2, l3);
    float conf = pos ? (float)(int)(sh_t[gi][4] + 1.0f) : 0.0f;
    out[(size_t)BB * AA * 4 + (size_t)b * AA + a] = conf;
}

extern "C" void kernel_launch(void* const* d_in, const int* in_sizes, int n_in,
                              void* d_out, int out_size, void* d_ws, size_t ws_size,
                              hipStream_t stream) {
    const float* targets = (const float*)d_in[0];  // (B,T,5)
    const float* anchors = (const float*)d_in[1];  // (A,4)
    float* out = (float*)d_out;
    u64* keys = (u64*)d_ws;                                // 51.2 KB
    u16* pa = (u16*)((char*)d_ws + (size_t)BB * TT * 8);   // 1.09 MB

    k_init<<<(BB * TT + 255) / 256, 256, 0, stream>>>(keys);
    dim3 gA(NCHUNK, BB);
    k_phaseA<<<gA, NTHR, 0, stream>>>(targets, anchors, keys, pa);
    dim3 gE((AA + 255) / 256, BB);
    k_encode<<<gE, 256, 0, stream>>>(targets, anchors, keys, pa, out);
}